// Round 9
// baseline (236.807 us; speedup 1.0000x reference)
//
#include <hip/hip_runtime.h>

namespace {
constexpr int T = 512;
constexpr int BATCH = 512;
constexpr int D = 32;
constexpr int H = 64;
constexpr int THREADS = 256;  // 4 waves/row; lane = (j = tid>>2, q = tid&3)
}

typedef float v2f __attribute__((ext_vector_type(2)));

__device__ __forceinline__ float rcpf(float x) { return __builtin_amdgcn_rcpf(x); }
__device__ __forceinline__ float sigm(float x) { return rcpf(1.0f + __expf(-x)); }
__device__ __forceinline__ float tanh_fast(float x) {
    // 1 - 2/(e^{2x}+1); saturates via inf/0 at extremes
    return 1.0f - 2.0f * rcpf(__expf(2.0f * x) + 1.0f);
}

// packed fp32 FMA on native 64-bit vector registers: no operand repacking
__device__ __forceinline__ void pk2(v2f& acc, v2f w, v2f v) {
    asm("v_pk_fma_f32 %0, %1, %2, %0" : "+v"(acc) : "v"(w), "v"(v));
}

// sum across the 4 lanes of a DPP quad (lanes 4k..4k+3) — pure VALU, no LDS
__device__ __forceinline__ float quad_sum(float v) {
    int i = __builtin_bit_cast(int, v);
    float t = __builtin_bit_cast(float,
        __builtin_amdgcn_update_dpp(0, i, 0xB1, 0xF, 0xF, true)); // quad_perm [1,0,3,2]
    v += t;
    i = __builtin_bit_cast(int, v);
    t = __builtin_bit_cast(float,
        __builtin_amdgcn_update_dpp(0, i, 0x4E, 0xF, 0xF, true)); // quad_perm [2,3,0,1]
    return v + t;
}

// __launch_bounds__(256, 2): min 2 waves/EU -> VGPR cap ~256. Without this the
// compiler capped at 64 VGPR (targeting occupancy we can't use: grid-limited
// to 2 blocks/CU) and evicted the 72-float weight set from registers (R8: 236us).
__global__ __launch_bounds__(THREADS, 2) void gru_fused_kernel(
    const float* __restrict__ x,
    const float* __restrict__ w_ih_f, const float* __restrict__ w_hh_f,
    const float* __restrict__ b_ih_f, const float* __restrict__ b_hh_f,
    const float* __restrict__ w_ih_b, const float* __restrict__ b_ih_b,
    const float* __restrict__ b_hh_b,
    const float* __restrict__ fc1_w, const float* __restrict__ fc1_b,
    const float* __restrict__ fc2_w, const float* __restrict__ fc2_b,
    float* __restrict__ out)
{
    const int b   = blockIdx.x;   // batch row
    const int tid = threadIdx.x;
    const int j   = tid >> 2;     // h-index 0..63 — owns all 3 gates for this j
    const int q   = tid & 3;      // K-split quarter (= DPP quad lane)
    const int kh0 = q * 16;       // h-k slice [kh0, kh0+16)
    const int kx0 = q * 8;        // x-k slice [kx0, kx0+8)

    __shared__ __align__(16) float h_lds[2][H];      // double-buffered h
    __shared__ float last_lds[2 * H];

    // ---- per-lane weight slices in registers as native v2f (72 floats) ----
    v2f wr2[8], wz2[8], wn2[8], ur2[4], uz2[4], un2[4];
    {
        const v2f* pr = reinterpret_cast<const v2f*>(w_hh_f + (size_t)j * H + kh0);
        const v2f* pz = reinterpret_cast<const v2f*>(w_hh_f + (size_t)(H + j) * H + kh0);
        const v2f* pn = reinterpret_cast<const v2f*>(w_hh_f + (size_t)(2 * H + j) * H + kh0);
        #pragma unroll
        for (int m = 0; m < 8; ++m) { wr2[m] = pr[m]; wz2[m] = pz[m]; wn2[m] = pn[m]; }
        const v2f* qr = reinterpret_cast<const v2f*>(w_ih_f + (size_t)j * D + kx0);
        const v2f* qz = reinterpret_cast<const v2f*>(w_ih_f + (size_t)(H + j) * D + kx0);
        const v2f* qn = reinterpret_cast<const v2f*>(w_ih_f + (size_t)(2 * H + j) * D + kx0);
        #pragma unroll
        for (int m = 0; m < 4; ++m) { ur2[m] = qr[m]; uz2[m] = qz[m]; un2[m] = qn[m]; }
    }

    // biases: added exactly ONCE, AFTER the quad reduction
    const float pre_r  = b_ih_f[j]         + b_hh_f[j];
    const float pre_z  = b_ih_f[H + j]     + b_hh_f[H + j];
    const float pre_nx = b_ih_f[2 * H + j];
    const float pre_nh = b_hh_f[2 * H + j];

    const float* xrow = x + (size_t)b * T * D;

    if (tid < H) h_lds[0][tid] = 0.0f;

    // ---- x partials for t=0 (unreduced) + register-prefetch x[1] ----
    v2f axr = {0.f, 0.f}, axz = {0.f, 0.f}, axn = {0.f, 0.f};
    {
        const v2f* px = reinterpret_cast<const v2f*>(xrow + kx0);
        v2f x0 = px[0], x1 = px[1], x2 = px[2], x3 = px[3];
        pk2(axr, ur2[0], x0); pk2(axr, ur2[1], x1); pk2(axr, ur2[2], x2); pk2(axr, ur2[3], x3);
        pk2(axz, uz2[0], x0); pk2(axz, uz2[1], x1); pk2(axz, uz2[2], x2); pk2(axz, uz2[3], x3);
        pk2(axn, un2[0], x0); pk2(axn, un2[1], x1); pk2(axn, un2[2], x2); pk2(axn, un2[3], x3);
    }
    v2f nx0, nx1, nx2, nx3;   // x[t+1] slice, prefetched from global (vmcnt queue)
    {
        const v2f* px = reinterpret_cast<const v2f*>(xrow + D + kx0);
        nx0 = px[0]; nx1 = px[1]; nx2 = px[2]; nx3 = px[3];
    }

    __syncthreads();

    float hold = 0.0f;

    for (int t = 0; t < T; ++t) {
        const int cur = t & 1, nxt = cur ^ 1;

        // h slice (issue all 8 ds_read_b64 up front)
        v2f hh[8];
        {
            const v2f* hp = reinterpret_cast<const v2f*>(&h_lds[cur][kh0]);
            #pragma unroll
            for (int m = 0; m < 8; ++m) hh[m] = hp[m];
        }

        // h-dot seeded with this step's x partials: 24 pk2
        v2f pr = axr, pz = axz, nh = {0.f, 0.f};
        #pragma unroll
        for (int m = 0; m < 8; ++m) pk2(pr, wr2[m], hh[m]);
        #pragma unroll
        for (int m = 0; m < 8; ++m) pk2(pz, wz2[m], hh[m]);
        #pragma unroll
        for (int m = 0; m < 8; ++m) pk2(nh, wn2[m], hh[m]);
        const v2f axn_t = axn;   // n-gate x partial for THIS step

        // x partials for t+1 (independent of h — fills reduce/trans latency)
        axr = {0.f, 0.f}; axz = {0.f, 0.f}; axn = {0.f, 0.f};
        pk2(axr, ur2[0], nx0); pk2(axr, ur2[1], nx1); pk2(axr, ur2[2], nx2); pk2(axr, ur2[3], nx3);
        pk2(axz, uz2[0], nx0); pk2(axz, uz2[1], nx1); pk2(axz, uz2[2], nx2); pk2(axz, uz2[3], nx3);
        pk2(axn, un2[0], nx0); pk2(axn, un2[1], nx1); pk2(axn, un2[2], nx2); pk2(axn, un2[3], nx3);

        // register-prefetch x[t+2] (global, broadcast across quads; ~1 full
        // step of latency budget before consumption)
        {
            const v2f* px = reinterpret_cast<const v2f*>(
                xrow + ((t + 2) & (T - 1)) * D + kx0);
            nx0 = px[0]; nx1 = px[1]; nx2 = px[2]; nx3 = px[3];
        }

        // quad reduction: 4 interleaved pure-VALU DPP butterflies
        const float vr  = quad_sum(pr.x + pr.y);
        const float vz  = quad_sum(pz.x + pz.y);
        const float vnh = quad_sum(nh.x + nh.y);
        const float vnx = quad_sum(axn_t.x + axn_t.y);

        const float r = sigm(vr + pre_r);
        const float z = sigm(vz + pre_z);
        const float n = tanh_fast(vnx + pre_nx + r * (vnh + pre_nh));
        const float hnew = n + z * (hold - n);   // (1-z)n + z*hold
        hold = hnew;
        if (q == 0) h_lds[nxt][j] = hnew;
        __syncthreads();   // single barrier per step
    }

    // ---- epilogue ----
    const int wave = tid >> 6, lane = tid & 63;

    // forward final state (T even -> buffer 0)
    if (wave == 0) last_lds[lane] = h_lds[T & 1][lane];

    // backward direction: exactly ONE step from h0 = 0 on x[b][T-1][:]
    if (wave == 1) {
        const float* xT = xrow + (size_t)(T - 1) * D;
        const int jj = lane;
        float xr = b_ih_b[jj];
        float xz = b_ih_b[H + jj];
        float xn = b_ih_b[2 * H + jj];
        #pragma unroll
        for (int k = 0; k < D; ++k) {
            const float xv = xT[k];
            xr = fmaf(w_ih_b[(size_t)jj * D + k],           xv, xr);
            xz = fmaf(w_ih_b[(size_t)(H + jj) * D + k],     xv, xz);
            xn = fmaf(w_ih_b[(size_t)(2 * H + jj) * D + k], xv, xn);
        }
        const float r = sigm(xr + b_hh_b[jj]);
        const float z = sigm(xz + b_hh_b[H + jj]);
        const float n = tanh_fast(xn + r * b_hh_b[2 * H + jj]);
        last_lds[H + jj] = (1.0f - z) * n;   // z*h0 = 0
    }
    __syncthreads();

    // head: h1 = leaky(fc1_w @ last + fc1_b); out = fc2_w @ h1 + fc2_b
    if (wave == 0) {
        float acc = fc1_b[lane];
        const float* w1 = fc1_w + (size_t)lane * (2 * H);
        #pragma unroll 8
        for (int c = 0; c < 2 * H; ++c) acc = fmaf(w1[c], last_lds[c], acc);
        acc = (acc >= 0.0f) ? acc : 0.2f * acc;
        float red = acc * fc2_w[lane];
        #pragma unroll
        for (int off = 32; off > 0; off >>= 1)
            red += __shfl_down(red, off);
        if (lane == 0) out[b] = red + fc2_b[0];
    }
}

extern "C" void kernel_launch(void* const* d_in, const int* in_sizes, int n_in,
                              void* d_out, int out_size, void* d_ws, size_t ws_size,
                              hipStream_t stream) {
    const float* x      = (const float*)d_in[0];
    const float* w_ih_f = (const float*)d_in[1];
    const float* w_hh_f = (const float*)d_in[2];
    const float* b_ih_f = (const float*)d_in[3];
    const float* b_hh_f = (const float*)d_in[4];
    const float* w_ih_b = (const float*)d_in[5];
    // d_in[6] = w_hh_b: unused (backward direction runs exactly one step from h0=0)
    const float* b_ih_b = (const float*)d_in[7];
    const float* b_hh_b = (const float*)d_in[8];
    const float* fc1_w  = (const float*)d_in[9];
    const float* fc1_b  = (const float*)d_in[10];
    const float* fc2_w  = (const float*)d_in[11];
    const float* fc2_b  = (const float*)d_in[12];
    float* out = (float*)d_out;

    gru_fused_kernel<<<BATCH, THREADS, 0, stream>>>(
        x, w_ih_f, w_hh_f, b_ih_f, b_hh_f,
        w_ih_b, b_ih_b, b_hh_b,
        fc1_w, fc1_b, fc2_w, fc2_b, out);
}

// Round 10
// 203.403 us; speedup vs baseline: 1.1642x; 1.1642x over previous
//
#include <hip/hip_runtime.h>

namespace {
constexpr int T = 512;
constexpr int BATCH = 512;
constexpr int D = 32;
constexpr int H = 64;
constexpr int THREADS = 128;  // 2 waves/row; lane pair (2j,2j+1) shares h-index j
}

typedef float v2f __attribute__((ext_vector_type(2)));

__device__ __forceinline__ float rcpf(float x) { return __builtin_amdgcn_rcpf(x); }
__device__ __forceinline__ float sigm(float x) { return rcpf(1.0f + __expf(-x)); }
__device__ __forceinline__ float tanh_fast(float x) {
    // 1 - 2/(e^{2x}+1); saturates via inf/0 at extremes
    return 1.0f - 2.0f * rcpf(__expf(2.0f * x) + 1.0f);
}

// packed fp32 FMA on native 64-bit vector registers: no operand repacking
__device__ __forceinline__ void pk2(v2f& acc, v2f w, v2f v) {
    asm("v_pk_fma_f32 %0, %1, %2, %0" : "+v"(acc) : "v"(w), "v"(v));
}

// sum across a lane pair (l, l^1) — single DPP quad_perm [1,0,3,2], pure VALU
__device__ __forceinline__ float pair_sum(float v) {
    int i = __builtin_bit_cast(int, v);
    float t = __builtin_bit_cast(float,
        __builtin_amdgcn_update_dpp(0, i, 0xB1, 0xF, 0xF, true));
    return v + t;
}

// min 1 wave/EU -> VGPR cap 512: we WANT ~200 resident (72 v2f weights + temps).
__global__ __launch_bounds__(THREADS, 1) void gru_fused_kernel(
    const float* __restrict__ x,
    const float* __restrict__ w_ih_f, const float* __restrict__ w_hh_f,
    const float* __restrict__ b_ih_f, const float* __restrict__ b_hh_f,
    const float* __restrict__ w_ih_b, const float* __restrict__ b_ih_b,
    const float* __restrict__ b_hh_b,
    const float* __restrict__ fc1_w, const float* __restrict__ fc1_b,
    const float* __restrict__ fc2_w, const float* __restrict__ fc2_b,
    float* __restrict__ out)
{
    const int b   = blockIdx.x;   // batch row
    const int tid = threadIdx.x;
    const int j   = tid >> 1;     // h-index 0..63 — owns all 3 gates for this j
    const int q   = tid & 1;      // K-split half (= DPP pair lane)
    const int kh0 = q * 32;       // h-k slice [kh0, kh0+32)
    const int kx0 = q * 16;       // x-k slice [kx0, kx0+16)

    __shared__ v2f x_lds[T * D / 2];                 // 64 KB staged x row
    __shared__ __align__(16) float h_lds[2][H];      // double-buffered h
    __shared__ float last_lds[2 * H];

    // ---- per-lane weight slices in registers as native v2f (144 floats) ----
    v2f wr2[16], wz2[16], wn2[16], ur2[8], uz2[8], un2[8];
    {
        const v2f* pr = reinterpret_cast<const v2f*>(w_hh_f + (size_t)j * H + kh0);
        const v2f* pz = reinterpret_cast<const v2f*>(w_hh_f + (size_t)(H + j) * H + kh0);
        const v2f* pn = reinterpret_cast<const v2f*>(w_hh_f + (size_t)(2 * H + j) * H + kh0);
        #pragma unroll
        for (int m = 0; m < 16; ++m) { wr2[m] = pr[m]; wz2[m] = pz[m]; wn2[m] = pn[m]; }
        const v2f* qr = reinterpret_cast<const v2f*>(w_ih_f + (size_t)j * D + kx0);
        const v2f* qz = reinterpret_cast<const v2f*>(w_ih_f + (size_t)(H + j) * D + kx0);
        const v2f* qn = reinterpret_cast<const v2f*>(w_ih_f + (size_t)(2 * H + j) * D + kx0);
        #pragma unroll
        for (int m = 0; m < 8; ++m) { ur2[m] = qr[m]; uz2[m] = qz[m]; un2[m] = qn[m]; }
    }

    // biases: added exactly ONCE, AFTER the pair reduction
    const float pre_r  = b_ih_f[j]         + b_hh_f[j];
    const float pre_z  = b_ih_f[H + j]     + b_hh_f[H + j];
    const float pre_nx = b_ih_f[2 * H + j];
    const float pre_nh = b_hh_f[2 * H + j];

    // ---- stage x row into LDS (coalesced float4) ----
    {
        const float4* xg  = reinterpret_cast<const float4*>(x + (size_t)b * T * D);
        float4*       xl4 = reinterpret_cast<float4*>(x_lds);
        #pragma unroll 4
        for (int i = tid; i < T * D / 4; i += THREADS) xl4[i] = xg[i];
    }
    if (tid < H) h_lds[0][tid] = 0.0f;
    __syncthreads();

    // ---- x partials for t=0 (bias-free, unreduced) ----
    v2f axr = {0.f, 0.f}, axz = {0.f, 0.f}, axn = {0.f, 0.f};
    {
        const v2f* xt2 = x_lds + q * 8;   // t=0
        #pragma unroll
        for (int m = 0; m < 8; ++m) {
            v2f xv = xt2[m];
            pk2(axr, ur2[m], xv);
            pk2(axz, uz2[m], xv);
            pk2(axn, un2[m], xv);
        }
    }

    float hold = 0.0f;

    for (int t = 0; t < T; ++t) {
        const int cur = t & 1, nxt = cur ^ 1;

        // h slice: 32 floats as 16 v2f (contiguous -> ds_read_b128 bursts)
        v2f hh[16];
        {
            const v2f* hp = reinterpret_cast<const v2f*>(&h_lds[cur][kh0]);
            #pragma unroll
            for (int m = 0; m < 16; ++m) hh[m] = hp[m];
        }

        // h-dot seeded with this step's x partials: 48 pk2
        v2f pr = axr, pz = axz, nh = {0.f, 0.f};
        #pragma unroll
        for (int m = 0; m < 16; ++m) pk2(pr, wr2[m], hh[m]);
        #pragma unroll
        for (int m = 0; m < 16; ++m) pk2(pz, wz2[m], hh[m]);
        #pragma unroll
        for (int m = 0; m < 16; ++m) pk2(nh, wn2[m], hh[m]);
        const v2f axn_t = axn;   // n-gate x partial for THIS step

        // x partials for t+1 (independent of h — fills reduce/trans latency)
        {
            const int tn = (t + 1) & (T - 1);
            const v2f* xt2 = x_lds + tn * (D / 2) + q * 8;
            axr = {0.f, 0.f}; axz = {0.f, 0.f}; axn = {0.f, 0.f};
            #pragma unroll
            for (int m = 0; m < 8; ++m) {
                v2f xv = xt2[m];
                pk2(axr, ur2[m], xv);
                pk2(axz, uz2[m], xv);
                pk2(axn, un2[m], xv);
            }
        }

        // pair reduction: single DPP butterfly each, pure VALU
        const float vr  = pair_sum(pr.x + pr.y);
        const float vz  = pair_sum(pz.x + pz.y);
        const float vnh = pair_sum(nh.x + nh.y);
        const float vnx = pair_sum(axn_t.x + axn_t.y);

        const float r = sigm(vr + pre_r);
        const float z = sigm(vz + pre_z);
        const float n = tanh_fast(vnx + pre_nx + r * (vnh + pre_nh));
        const float hnew = n + z * (hold - n);   // (1-z)n + z*hold
        hold = hnew;
        if (q == 0) h_lds[nxt][j] = hnew;
        __syncthreads();   // single barrier per step, only 2 waves
    }

    // ---- epilogue ----
    const int wave = tid >> 6, lane = tid & 63;

    // forward final state (T even -> buffer 0)
    if (wave == 0) last_lds[lane] = h_lds[T & 1][lane];

    // backward direction: exactly ONE step from h0 = 0 on x[b][T-1][:]
    if (wave == 1) {
        const float* xT = reinterpret_cast<const float*>(x_lds) + (T - 1) * D;
        const int jj = lane;
        float xr = b_ih_b[jj];
        float xz = b_ih_b[H + jj];
        float xn = b_ih_b[2 * H + jj];
        #pragma unroll
        for (int k = 0; k < D; ++k) {
            const float xv = xT[k];
            xr = fmaf(w_ih_b[(size_t)jj * D + k],           xv, xr);
            xz = fmaf(w_ih_b[(size_t)(H + jj) * D + k],     xv, xz);
            xn = fmaf(w_ih_b[(size_t)(2 * H + jj) * D + k], xv, xn);
        }
        const float r = sigm(xr + b_hh_b[jj]);
        const float z = sigm(xz + b_hh_b[H + jj]);
        const float n = tanh_fast(xn + r * b_hh_b[2 * H + jj]);
        last_lds[H + jj] = (1.0f - z) * n;   // z*h0 = 0
    }
    __syncthreads();

    // head: h1 = leaky(fc1_w @ last + fc1_b); out = fc2_w @ h1 + fc2_b
    if (wave == 0) {
        float acc = fc1_b[lane];
        const float* w1 = fc1_w + (size_t)lane * (2 * H);
        #pragma unroll 8
        for (int c = 0; c < 2 * H; ++c) acc = fmaf(w1[c], last_lds[c], acc);
        acc = (acc >= 0.0f) ? acc : 0.2f * acc;
        float red = acc * fc2_w[lane];
        #pragma unroll
        for (int off = 32; off > 0; off >>= 1)
            red += __shfl_down(red, off);
        if (lane == 0) out[b] = red + fc2_b[0];
    }
}

extern "C" void kernel_launch(void* const* d_in, const int* in_sizes, int n_in,
                              void* d_out, int out_size, void* d_ws, size_t ws_size,
                              hipStream_t stream) {
    const float* x      = (const float*)d_in[0];
    const float* w_ih_f = (const float*)d_in[1];
    const float* w_hh_f = (const float*)d_in[2];
    const float* b_ih_f = (const float*)d_in[3];
    const float* b_hh_f = (const float*)d_in[4];
    const float* w_ih_b = (const float*)d_in[5];
    // d_in[6] = w_hh_b: unused (backward direction runs exactly one step from h0=0)
    const float* b_ih_b = (const float*)d_in[7];
    const float* b_hh_b = (const float*)d_in[8];
    const float* fc1_w  = (const float*)d_in[9];
    const float* fc1_b  = (const float*)d_in[10];
    const float* fc2_w  = (const float*)d_in[11];
    const float* fc2_b  = (const float*)d_in[12];
    float* out = (float*)d_out;

    gru_fused_kernel<<<BATCH, THREADS, 0, stream>>>(
        x, w_ih_f, w_hh_f, b_ih_f, b_hh_f,
        w_ih_b, b_ih_b, b_hh_b,
        fc1_w, fc1_b, fc2_w, fc2_b, out);
}